// Round 1
// baseline (18695.804 us; speedup 1.0000x reference)
//
#include <hip/hip_runtime.h>
#include <stdint.h>

#define NN 8192
#define DD 768
#define F0 (-9.0109133f)                 // -ln(8192)
#define LOG2E 1.4426950408889634f
#define LN2 0.6931471805599453f

typedef unsigned int  U32;
typedef unsigned short U16;

// monotonic float->uint key for atomicMax on floats
__device__ __forceinline__ U32 fkey(float x){
  U32 u = __float_as_uint(x);
  return (u & 0x80000000u) ? ~u : (u | 0x80000000u);
}
__device__ __forceinline__ float funkey(U32 k){
  return __uint_as_float((k & 0x80000000u) ? (k ^ 0x80000000u) : ~k);
}
__device__ __forceinline__ float ex2(float x){ return __builtin_amdgcn_exp2f(x); }
__device__ __forceinline__ float lg2(float x){ return __log2f(x); }

// slots: 0 qmax(u32) 1 qmin(u32) 2 maxsqA key 3 maxsqB key 4 maxf key 5 maxg key 6 Cg bits
__global__ __launch_bounds__(256) void k_init(float* f, float* g, U32* slots){
  int t = blockIdx.x*256 + threadIdx.x;
  if (t < NN){ f[t] = F0; g[t] = F0; }
  if (t == 0){
    slots[0]=0u; slots[1]=0xFFFFFFFFu; slots[2]=0u; slots[3]=0u;
    slots[4]=fkey(F0); slots[5]=0u; slots[6]=0u;
  }
}

__global__ __launch_bounds__(256) void k_sqsum(const float* __restrict__ A, const float* __restrict__ B,
                                               float* sqA, float* sqB, U32* slots){
  int wv = threadIdx.x >> 6, ln = threadIdx.x & 63;
  int row = blockIdx.x*4 + wv;
  const float* src = A; float* dst = sqA; U32* slot = slots + 2; int r = row;
  if (row >= NN){ src = B; dst = sqB; slot = slots + 3; r = row - NN; }
  const float* p = src + (size_t)r * DD;
  float s = 0.f;
  #pragma unroll
  for (int m = 0; m < DD/64; ++m){ float v = p[ln + 64*m]; s = fmaf(v, v, s); }
  #pragma unroll
  for (int o = 32; o; o >>= 1) s += __shfl_xor(s, o);
  if (ln == 0){ dst[r] = s; atomicMax(slot, fkey(s)); }
}

// 128x128 tile fp32 Gram -> dist -> u16 quantize; track qmax/qmin
__global__ __launch_bounds__(256) void k_dist(const float* __restrict__ A, const float* __restrict__ B,
                                              U16* __restrict__ q, const float* __restrict__ sqA,
                                              const float* __restrict__ sqB, U32* slots){
  __shared__ float As[16][128], Bs[16][128];
  __shared__ U32 redmx[4], redmn[4];
  const int t = threadIdx.x;
  const int i0 = blockIdx.y*128, j0 = blockIdx.x*128;
  const float S = 65535.f / (sqrtf(funkey(slots[2])) + sqrtf(funkey(slots[3])));
  float acc[8][8];
  #pragma unroll
  for (int m=0;m<8;m++)
    #pragma unroll
    for (int n=0;n<8;n++) acc[m][n] = 0.f;
  const int lr = t >> 1, lk = (t & 1)*8;
  const float* pa = A + (size_t)(i0+lr)*DD + lk;
  const float* pb = B + (size_t)(j0+lr)*DD + lk;
  const int tx = t & 15, ty = t >> 4;
  for (int k0 = 0; k0 < DD; k0 += 16){
    __syncthreads();
    float4 a0 = *(const float4*)(pa + k0);
    float4 a1 = *(const float4*)(pa + k0 + 4);
    float4 b0 = *(const float4*)(pb + k0);
    float4 b1 = *(const float4*)(pb + k0 + 4);
    As[lk+0][lr]=a0.x; As[lk+1][lr]=a0.y; As[lk+2][lr]=a0.z; As[lk+3][lr]=a0.w;
    As[lk+4][lr]=a1.x; As[lk+5][lr]=a1.y; As[lk+6][lr]=a1.z; As[lk+7][lr]=a1.w;
    Bs[lk+0][lr]=b0.x; Bs[lk+1][lr]=b0.y; Bs[lk+2][lr]=b0.z; Bs[lk+3][lr]=b0.w;
    Bs[lk+4][lr]=b1.x; Bs[lk+5][lr]=b1.y; Bs[lk+6][lr]=b1.z; Bs[lk+7][lr]=b1.w;
    __syncthreads();
    #pragma unroll
    for (int kk = 0; kk < 16; ++kk){
      float4 am0 = *(const float4*)&As[kk][ty*8];
      float4 am1 = *(const float4*)&As[kk][ty*8+4];
      float4 bn0 = *(const float4*)&Bs[kk][tx*8];
      float4 bn1 = *(const float4*)&Bs[kk][tx*8+4];
      float ar[8] = {am0.x,am0.y,am0.z,am0.w,am1.x,am1.y,am1.z,am1.w};
      float br[8] = {bn0.x,bn0.y,bn0.z,bn0.w,bn1.x,bn1.y,bn1.z,bn1.w};
      #pragma unroll
      for (int m=0;m<8;m++)
        #pragma unroll
        for (int n=0;n<8;n++) acc[m][n] = fmaf(ar[m], br[n], acc[m][n]);
    }
  }
  U32 bmax = 0u, bmin = 0xFFFFu;
  #pragma unroll
  for (int m=0;m<8;m++){
    int i = i0 + ty*8 + m;
    float sa = sqA[i];
    U16 pk[8] __attribute__((aligned(16)));
    #pragma unroll
    for (int n=0;n<8;n++){
      int j = j0 + tx*8 + n;
      float sq = sa + sqB[j] - 2.f*acc[m][n];
      float d = sqrtf(fmaxf(sq, 0.f));
      d = fmaxf(d, 1e-6f);
      U32 qv = (U32)rintf(d * S);
      if (qv > 65535u) qv = 65535u;
      bmax = bmax > qv ? bmax : qv;
      bmin = bmin < qv ? bmin : qv;
      pk[n] = (U16)qv;
    }
    *(uint4*)(q + (size_t)i*NN + j0 + tx*8) = *(const uint4*)pk;
  }
  #pragma unroll
  for (int o=32;o;o>>=1){
    U32 om = __shfl_xor(bmax, o); bmax = bmax > om ? bmax : om;
    U32 on = __shfl_xor(bmin, o); bmin = bmin < on ? bmin : on;
  }
  if ((t & 63) == 0){ redmx[t>>6] = bmax; redmn[t>>6] = bmin; }
  __syncthreads();
  if (t == 0){
    U32 mx = redmx[0], mn = redmn[0];
    #pragma unroll
    for (int i=1;i<4;i++){ mx = mx > redmx[i] ? mx : redmx[i]; mn = mn < redmn[i] ? mn : redmn[i]; }
    atomicMax(slots+0, mx); atomicMin(slots+1, mn);
  }
}

// col-LSE partial: block = 512 cols x 128 rows, fixed shift Cg = maxf - 50(1+qmin/qmax)
__global__ __launch_bounds__(256) void k_g_partial(const U32* __restrict__ q32, const float* __restrict__ f,
                                                   float* __restrict__ part, U32* slots){
  __shared__ float fl[128];
  const int t = threadIdx.x;
  const int c0 = blockIdx.x * 512;
  const int r0 = blockIdx.y * 128;
  const float qmaxf = (float)slots[0];
  const float r0n = (float)slots[1] / qmaxf;
  const float maxf = funkey(slots[4]);
  const float Cg = maxf - 50.f*(1.f + r0n);
  const float k1 = -100.f*LOG2E/qmaxf, tcl = -1e-4f*LOG2E;
  if (t < 128) fl[t] = (f[r0 + t] - Cg) * LOG2E;
  if (blockIdx.x == 0 && blockIdx.y == 0 && t == 0){
    slots[5] = 0u;                       // reset maxg for this iteration
    slots[6] = __float_as_uint(Cg);      // publish Cg for finalize
  }
  __syncthreads();
  float a0 = 0.f, a1 = 0.f;
  const U32* p = q32 + (size_t)r0*(NN/2) + (c0 >> 1) + t;
  #pragma unroll 4
  for (int i = 0; i < 128; ++i){
    U32 w = p[(size_t)i*(NN/2)];
    float fi = fl[i];
    a0 += ex2(fminf((float)(w & 0xFFFFu)*k1, tcl) + fi);
    a1 += ex2(fminf((float)(w >> 16)*k1, tcl) + fi);
  }
  *(float2*)(part + (size_t)blockIdx.y*NN + c0 + 2*t) = make_float2(a0, a1);
}

__global__ __launch_bounds__(256) void k_g_fin(const float* __restrict__ part, float* __restrict__ g, U32* slots){
  const int t = threadIdx.x;
  const int c = blockIdx.x*256 + t;
  const float Cg = __uint_as_float(slots[6]);
  float s = 0.f;
  #pragma unroll 8
  for (int k = 0; k < 64; ++k) s += part[(size_t)k*NN + c];
  float gv = -(Cg + lg2(s)*LN2);
  g[c] = gv;
  float m = gv;
  #pragma unroll
  for (int o=32;o;o>>=1) m = fmaxf(m, __shfl_xor(m, o));
  if ((t & 63) == 0) atomicMax(slots+5, fkey(m));
  if (c == 0) slots[4] = 0u;             // reset maxf for upcoming f-update
}

// row-LSE: block = 8 rows (1 wave each), full g staged in LDS pre-scaled
__global__ __launch_bounds__(512) void k_f_upd(const U32* __restrict__ q32, const float* __restrict__ g,
                                               float* __restrict__ f, U32* slots){
  __shared__ float gl[NN];
  __shared__ float red[8];
  const int t = threadIdx.x;
  const float qmaxf = (float)slots[0];
  const float r0n = (float)slots[1] / qmaxf;
  const float maxg = funkey(slots[5]);
  const float Cf = maxg - 50.f*(1.f + r0n);
  const float k1 = -100.f*LOG2E/qmaxf, tcl = -1e-4f*LOG2E;
  #pragma unroll
  for (int m = 0; m < NN/512; ++m) gl[t + 512*m] = (g[t + 512*m] - Cf)*LOG2E;
  __syncthreads();
  const int wv = t >> 6, ln = t & 63;
  const int r = blockIdx.x*8 + wv;
  const U32* p = q32 + (size_t)r*(NN/2);
  float s = 0.f;
  #pragma unroll 4
  for (int k = 0; k < 64; ++k){
    U32 w = p[k*64 + ln];
    int j2 = (k*64 + ln)*2;
    s += ex2(fminf((float)(w & 0xFFFFu)*k1, tcl) + gl[j2]);
    s += ex2(fminf((float)(w >> 16)*k1, tcl) + gl[j2+1]);
  }
  #pragma unroll
  for (int o=32;o;o>>=1) s += __shfl_xor(s, o);
  float fv = -(Cf + lg2(s)*LN2);
  if (ln == 0){ f[r] = fv; red[wv] = fv; }
  __syncthreads();
  if (t == 0){
    float m = red[0];
    #pragma unroll
    for (int i=1;i<8;i++) m = fmaxf(m, red[i]);
    atomicMax(slots+4, fkey(m));
  }
}

// aligned_A[i][d] = sum_j T[i][j] * A[j][d];  T generated on the fly into LDS
__global__ __launch_bounds__(256) void k_outA(const U16* __restrict__ q, const float* __restrict__ A,
                                              const float* __restrict__ f, const float* __restrict__ g,
                                              const U32* slots, float* __restrict__ outA){
  __shared__ float T[64][64];
  const int t = threadIdx.x;
  const int i0 = blockIdx.y*64, d0 = blockIdx.x*128;
  const float qmaxf = (float)slots[0];
  const float k1 = -100.f*LOG2E/qmaxf, tcl = -1e-4f*LOG2E;
  const int jc = t & 63, ig = t >> 6;
  const int dg = t & 31, ig2 = t >> 5;
  float4 acc[8];
  #pragma unroll
  for (int m=0;m<8;m++) acc[m] = make_float4(0.f,0.f,0.f,0.f);
  for (int j0 = 0; j0 < NN; j0 += 64){
    __syncthreads();
    float gj = g[j0 + jc];
    #pragma unroll
    for (int m=0;m<16;m++){
      int i = i0 + ig*16 + m;
      float qv = (float)q[(size_t)i*NN + j0 + jc];
      T[ig*16+m][jc] = ex2(fminf(qv*k1, tcl) + (f[i] + gj)*LOG2E);
    }
    __syncthreads();
    #pragma unroll 4
    for (int jj = 0; jj < 64; ++jj){
      float4 a4 = *(const float4*)(A + (size_t)(j0+jj)*DD + d0 + dg*4);
      #pragma unroll
      for (int m=0;m<8;m++){
        float tv = T[ig2*8+m][jj];
        acc[m].x = fmaf(tv, a4.x, acc[m].x);
        acc[m].y = fmaf(tv, a4.y, acc[m].y);
        acc[m].z = fmaf(tv, a4.z, acc[m].z);
        acc[m].w = fmaf(tv, a4.w, acc[m].w);
      }
    }
  }
  #pragma unroll
  for (int m=0;m<8;m++){
    int i = i0 + ig2*8 + m;
    *(float4*)(outA + (size_t)i*DD + d0 + dg*4) = acc[m];
  }
}

// aligned_B[j][d] = sum_i T[i][j] * B[i][d];  transposed T tile in LDS (padded)
__global__ __launch_bounds__(256) void k_outB(const U16* __restrict__ q, const float* __restrict__ B,
                                              const float* __restrict__ f, const float* __restrict__ g,
                                              const U32* slots, float* __restrict__ outB){
  __shared__ float Tt[64][65];
  const int t = threadIdx.x;
  const int j0t = blockIdx.y*64, d0 = blockIdx.x*128;
  const float qmaxf = (float)slots[0];
  const float k1 = -100.f*LOG2E/qmaxf, tcl = -1e-4f*LOG2E;
  const int jc = t & 63, ig = t >> 6;
  const int dg = t & 31, jg = t >> 5;
  float4 acc[8];
  #pragma unroll
  for (int m=0;m<8;m++) acc[m] = make_float4(0.f,0.f,0.f,0.f);
  const float gj = g[j0t + jc];
  for (int i0 = 0; i0 < NN; i0 += 64){
    __syncthreads();
    #pragma unroll
    for (int m=0;m<16;m++){
      int i = i0 + ig*16 + m;
      float qv = (float)q[(size_t)i*NN + j0t + jc];
      Tt[jc][ig*16+m] = ex2(fminf(qv*k1, tcl) + (f[i] + gj)*LOG2E);
    }
    __syncthreads();
    #pragma unroll 4
    for (int ii = 0; ii < 64; ++ii){
      float4 b4 = *(const float4*)(B + (size_t)(i0+ii)*DD + d0 + dg*4);
      #pragma unroll
      for (int m=0;m<8;m++){
        float tv = Tt[jg*8+m][ii];
        acc[m].x = fmaf(tv, b4.x, acc[m].x);
        acc[m].y = fmaf(tv, b4.y, acc[m].y);
        acc[m].z = fmaf(tv, b4.z, acc[m].z);
        acc[m].w = fmaf(tv, b4.w, acc[m].w);
      }
    }
  }
  #pragma unroll
  for (int m=0;m<8;m++){
    int j = j0t + jg*8 + m;
    *(float4*)(outB + (size_t)j*DD + d0 + dg*4) = acc[m];
  }
}

extern "C" void kernel_launch(void* const* d_in, const int* in_sizes, int n_in,
                              void* d_out, int out_size, void* d_ws, size_t ws_size,
                              hipStream_t stream) {
  const float* A = (const float*)d_in[0];
  const float* B = (const float*)d_in[1];
  float* out = (float*)d_out;
  char* ws = (char*)d_ws;
  // ws layout (~136.5 MB):
  U16*  q     = (U16*) (ws);                          // 8192*8192*2 = 134217728
  float* part = (float*)(ws + 134217728);             // 64*8192*4   = 2097152
  float* f    = (float*)(ws + 136314880);             // 32768
  float* g    = (float*)(ws + 136347648);             // 32768
  float* sqA  = (float*)(ws + 136380416);             // 32768
  float* sqB  = (float*)(ws + 136413184);             // 32768
  U32*  slots = (U32*) (ws + 136445952);              // scalars

  k_init<<<32, 256, 0, stream>>>(f, g, slots);
  k_sqsum<<<4096, 256, 0, stream>>>(A, B, sqA, sqB, slots);
  k_dist<<<dim3(64,64), 256, 0, stream>>>(A, B, q, sqA, sqB, slots);
  for (int it = 0; it < 200; ++it){
    k_g_partial<<<dim3(16,64), 256, 0, stream>>>((const U32*)q, f, part, slots);
    k_g_fin<<<32, 256, 0, stream>>>(part, g, slots);
    k_f_upd<<<1024, 512, 0, stream>>>((const U32*)q, g, f, slots);
  }
  k_outA<<<dim3(6,128), 256, 0, stream>>>(q, A, f, g, slots, out);
  k_outB<<<dim3(6,128), 256, 0, stream>>>(q, B, f, g, slots, out + (size_t)NN*DD);
}

// Round 2
// 15088.196 us; speedup vs baseline: 1.2391x; 1.2391x over previous
//
#include <hip/hip_runtime.h>
#include <stdint.h>

#define NN 8192
#define DD 768
#define LOG2E 1.4426950408889634f

typedef unsigned int  U32;
typedef unsigned short U16;

// monotonic float->uint key for atomicMax on floats
__device__ __forceinline__ U32 fkey(float x){
  U32 u = __float_as_uint(x);
  return (u & 0x80000000u) ? ~u : (u | 0x80000000u);
}
__device__ __forceinline__ float funkey(U32 k){
  return __uint_as_float((k & 0x80000000u) ? (k ^ 0x80000000u) : ~k);
}
__device__ __forceinline__ float ex2(float x){ return __builtin_amdgcn_exp2f(x); }
__device__ __forceinline__ float bflo(U32 w){ return __uint_as_float(w << 16); }
__device__ __forceinline__ float bfhi(U32 w){ return __uint_as_float(w & 0xFFFF0000u); }
// pack two floats to bf16x2 (RNE)
__device__ __forceinline__ U32 packbf(float lo, float hi){
  U32 a = __float_as_uint(lo), b = __float_as_uint(hi);
  a = a + 0x7FFFu + ((a >> 16) & 1u);
  b = b + 0x7FFFu + ((b >> 16) & 1u);
  return (a >> 16) | (b & 0xFFFF0000u);
}

// slots: 0 qmax(u32) 1 qmin(u32) 2 maxsqA key 3 maxsqB key
__global__ __launch_bounds__(256) void k_init(float* u, U32* slots){
  int t = blockIdx.x*256 + threadIdx.x;
  if (t < NN) u[t] = 1.0f/8192.0f;       // e^{-ln n} exactly (2^-13)
  if (t == 0){ slots[0]=0u; slots[1]=0xFFFFFFFFu; slots[2]=0u; slots[3]=0u; }
}

__global__ __launch_bounds__(256) void k_sqsum(const float* __restrict__ A, const float* __restrict__ B,
                                               float* sqA, float* sqB, U32* slots){
  int wv = threadIdx.x >> 6, ln = threadIdx.x & 63;
  int row = blockIdx.x*4 + wv;
  const float* src = A; float* dst = sqA; U32* slot = slots + 2; int r = row;
  if (row >= NN){ src = B; dst = sqB; slot = slots + 3; r = row - NN; }
  const float* p = src + (size_t)r * DD;
  float s = 0.f;
  #pragma unroll
  for (int m = 0; m < DD/64; ++m){ float v = p[ln + 64*m]; s = fmaf(v, v, s); }
  #pragma unroll
  for (int o = 32; o; o >>= 1) s += __shfl_xor(s, o);
  if (ln == 0){ dst[r] = s; atomicMax(slot, fkey(s)); }
}

// 128x128 tile fp32 Gram -> dist -> u16 quantize; track qmax/qmin
__global__ __launch_bounds__(256) void k_dist(const float* __restrict__ A, const float* __restrict__ B,
                                              U16* __restrict__ q, const float* __restrict__ sqA,
                                              const float* __restrict__ sqB, U32* slots){
  __shared__ float As[16][128], Bs[16][128];
  __shared__ U32 redmx[4], redmn[4];
  const int t = threadIdx.x;
  const int i0 = blockIdx.y*128, j0 = blockIdx.x*128;
  const float S = 65535.f / (sqrtf(funkey(slots[2])) + sqrtf(funkey(slots[3])));
  float acc[8][8];
  #pragma unroll
  for (int m=0;m<8;m++)
    #pragma unroll
    for (int n=0;n<8;n++) acc[m][n] = 0.f;
  const int lr = t >> 1, lk = (t & 1)*8;
  const float* pa = A + (size_t)(i0+lr)*DD + lk;
  const float* pb = B + (size_t)(j0+lr)*DD + lk;
  const int tx = t & 15, ty = t >> 4;
  for (int k0 = 0; k0 < DD; k0 += 16){
    __syncthreads();
    float4 a0 = *(const float4*)(pa + k0);
    float4 a1 = *(const float4*)(pa + k0 + 4);
    float4 b0 = *(const float4*)(pb + k0);
    float4 b1 = *(const float4*)(pb + k0 + 4);
    As[lk+0][lr]=a0.x; As[lk+1][lr]=a0.y; As[lk+2][lr]=a0.z; As[lk+3][lr]=a0.w;
    As[lk+4][lr]=a1.x; As[lk+5][lr]=a1.y; As[lk+6][lr]=a1.z; As[lk+7][lr]=a1.w;
    Bs[lk+0][lr]=b0.x; Bs[lk+1][lr]=b0.y; Bs[lk+2][lr]=b0.z; Bs[lk+3][lr]=b0.w;
    Bs[lk+4][lr]=b1.x; Bs[lk+5][lr]=b1.y; Bs[lk+6][lr]=b1.z; Bs[lk+7][lr]=b1.w;
    __syncthreads();
    #pragma unroll
    for (int kk = 0; kk < 16; ++kk){
      float4 am0 = *(const float4*)&As[kk][ty*8];
      float4 am1 = *(const float4*)&As[kk][ty*8+4];
      float4 bn0 = *(const float4*)&Bs[kk][tx*8];
      float4 bn1 = *(const float4*)&Bs[kk][tx*8+4];
      float ar[8] = {am0.x,am0.y,am0.z,am0.w,am1.x,am1.y,am1.z,am1.w};
      float br[8] = {bn0.x,bn0.y,bn0.z,bn0.w,bn1.x,bn1.y,bn1.z,bn1.w};
      #pragma unroll
      for (int m=0;m<8;m++)
        #pragma unroll
        for (int n=0;n<8;n++) acc[m][n] = fmaf(ar[m], br[n], acc[m][n]);
    }
  }
  U32 bmax = 0u, bmin = 0xFFFFu;
  #pragma unroll
  for (int m=0;m<8;m++){
    int i = i0 + ty*8 + m;
    float sa = sqA[i];
    U16 pk[8] __attribute__((aligned(16)));
    #pragma unroll
    for (int n=0;n<8;n++){
      int j = j0 + tx*8 + n;
      float sq = sa + sqB[j] - 2.f*acc[m][n];
      float d = sqrtf(fmaxf(sq, 0.f));
      d = fmaxf(d, 1e-6f);
      U32 qv = (U32)rintf(d * S);
      if (qv > 65535u) qv = 65535u;
      bmax = bmax > qv ? bmax : qv;
      bmin = bmin < qv ? bmin : qv;
      pk[n] = (U16)qv;
    }
    *(uint4*)(q + (size_t)i*NN + j0 + tx*8) = *(const uint4*)pk;
  }
  #pragma unroll
  for (int o=32;o;o>>=1){
    U32 om = __shfl_xor(bmax, o); bmax = bmax > om ? bmax : om;
    U32 on = __shfl_xor(bmin, o); bmin = bmin < on ? bmin : on;
  }
  if ((t & 63) == 0){ redmx[t>>6] = bmax; redmn[t>>6] = bmin; }
  __syncthreads();
  if (t == 0){
    U32 mx = redmx[0], mn = redmn[0];
    #pragma unroll
    for (int i=1;i<4;i++){ mx = mx > redmx[i] ? mx : redmx[i]; mn = mn < redmn[i] ? mn : redmn[i]; }
    atomicMax(slots+0, mx); atomicMin(slots+1, mn);
  }
}

// in-place u16 q -> bf16 K' = exp(logK + s), s = 50(1+qmin/qmax) ln-units.
// K' range e^{+-50(1-r0)}, bf16-safe for any data.
__global__ __launch_bounds__(256) void k_buildK(U32* K2, const U32* __restrict__ slots){
  const float qmaxf = (float)slots[0];
  const float r0n = (float)slots[1] / qmaxf;
  const float k1 = -100.f*LOG2E/qmaxf;
  const float c2 = 50.f*(1.f + r0n)*LOG2E;
  const float tcl = -1e-4f*LOG2E;
  size_t base = ((size_t)blockIdx.x*256 + threadIdx.x)*4;
  uint4 w = *(uint4*)(K2 + base);
  U32 r[4];
  U32 in[4] = {w.x, w.y, w.z, w.w};
  #pragma unroll
  for (int k=0;k<4;++k){
    float ql = (float)(in[k] & 0xFFFFu);
    float qh = (float)(in[k] >> 16);
    float el = ex2(fminf(ql*k1, tcl) + c2);
    float eh = ex2(fminf(qh*k1, tcl) + c2);
    r[k] = packbf(el, eh);
  }
  *(uint4*)(K2 + base) = make_uint4(r[0], r[1], r[2], r[3]);
}

// column partial sums: part[rc][j] = sum_{i in chunk rc} K'[i][j] * u[i]
__global__ __launch_bounds__(256) void k_col(const U32* __restrict__ K2, const float* __restrict__ u,
                                             float* __restrict__ part){
  __shared__ float ul[128];
  const int t = threadIdx.x;
  const int cc = blockIdx.x;          // 8 chunks of 1024 cols
  const int rc = blockIdx.y;          // 64 chunks of 128 rows
  const int r0 = rc*128;
  if (t < 128) ul[t] = u[r0 + t];
  __syncthreads();
  float a0=0.f, a1=0.f, a2=0.f, a3=0.f;
  const U32* p = K2 + (size_t)r0*(NN/2) + cc*512 + t*2;
  #pragma unroll 8
  for (int i = 0; i < 128; ++i){
    uint2 w = *(const uint2*)(p + (size_t)i*(NN/2));
    float ui = ul[i];
    a0 = fmaf(bflo(w.x), ui, a0);
    a1 = fmaf(bfhi(w.x), ui, a1);
    a2 = fmaf(bflo(w.y), ui, a2);
    a3 = fmaf(bfhi(w.y), ui, a3);
  }
  *(float4*)(part + (size_t)rc*NN + cc*1024 + t*4) = make_float4(a0,a1,a2,a3);
}

// v' = 1 / colsum
__global__ __launch_bounds__(128) void k_vfin(const float* __restrict__ part, float* __restrict__ v){
  const int c = blockIdx.x*128 + threadIdx.x;
  float s = 0.f;
  #pragma unroll 8
  for (int k = 0; k < 64; ++k) s += part[(size_t)k*NN + c];
  v[c] = 1.0f / s;
}

// row sums + u = 1/rowsum; v' staged in LDS
__global__ __launch_bounds__(512) void k_row(const U32* __restrict__ K2, const float* __restrict__ v,
                                             float* __restrict__ u){
  __shared__ float vl[NN];
  const int t = threadIdx.x;
  #pragma unroll
  for (int m = 0; m < NN/512; ++m) vl[t + 512*m] = v[t + 512*m];
  __syncthreads();
  const int wv = t >> 6, ln = t & 63;
  const int r = blockIdx.x*8 + wv;
  const uint4* p = (const uint4*)(K2 + (size_t)r*(NN/2));
  float s = 0.f;
  #pragma unroll 4
  for (int k = 0; k < 16; ++k){
    uint4 w = p[k*64 + ln];
    float4 v0 = *(const float4*)&vl[k*512 + ln*8];
    float4 v1 = *(const float4*)&vl[k*512 + ln*8 + 4];
    s = fmaf(bflo(w.x), v0.x, s); s = fmaf(bfhi(w.x), v0.y, s);
    s = fmaf(bflo(w.y), v0.z, s); s = fmaf(bfhi(w.y), v0.w, s);
    s = fmaf(bflo(w.z), v1.x, s); s = fmaf(bfhi(w.z), v1.y, s);
    s = fmaf(bflo(w.w), v1.z, s); s = fmaf(bfhi(w.w), v1.w, s);
  }
  #pragma unroll
  for (int o = 32; o; o >>= 1) s += __shfl_xor(s, o);
  if (ln == 0) u[r] = 1.0f / s;
}

// aligned_A[i][d] = u_i * sum_j K'[i][j] * (v'_j * A[j][d])
__global__ __launch_bounds__(256) void k_outA(const U16* __restrict__ Kp, const float* __restrict__ A,
                                              const float* __restrict__ u, const float* __restrict__ v,
                                              float* __restrict__ outA){
  __shared__ float T[64][64];
  const int t = threadIdx.x;
  const int i0 = blockIdx.y*64, d0 = blockIdx.x*128;
  const int jc = t & 63, ig = t >> 6;
  const int dg = t & 31, ig2 = t >> 5;
  float4 acc[8];
  #pragma unroll
  for (int m=0;m<8;m++) acc[m] = make_float4(0.f,0.f,0.f,0.f);
  for (int j0 = 0; j0 < NN; j0 += 64){
    __syncthreads();
    float vv = v[j0 + jc];
    #pragma unroll
    for (int m=0;m<16;m++){
      int i = i0 + ig*16 + m;
      U32 kb = ((U32)Kp[(size_t)i*NN + j0 + jc]) << 16;
      T[ig*16+m][jc] = __uint_as_float(kb) * vv;
    }
    __syncthreads();
    #pragma unroll 4
    for (int jj = 0; jj < 64; ++jj){
      float4 a4 = *(const float4*)(A + (size_t)(j0+jj)*DD + d0 + dg*4);
      #pragma unroll
      for (int m=0;m<8;m++){
        float tv = T[ig2*8+m][jj];
        acc[m].x = fmaf(tv, a4.x, acc[m].x);
        acc[m].y = fmaf(tv, a4.y, acc[m].y);
        acc[m].z = fmaf(tv, a4.z, acc[m].z);
        acc[m].w = fmaf(tv, a4.w, acc[m].w);
      }
    }
  }
  #pragma unroll
  for (int m=0;m<8;m++){
    int i = i0 + ig2*8 + m;
    float ui = u[i];
    acc[m].x *= ui; acc[m].y *= ui; acc[m].z *= ui; acc[m].w *= ui;
    *(float4*)(outA + (size_t)i*DD + d0 + dg*4) = acc[m];
  }
}

// aligned_B[j][d] = v'_j * sum_i (u_i * K'[i][j]) * B[i][d]
__global__ __launch_bounds__(256) void k_outB(const U16* __restrict__ Kp, const float* __restrict__ B,
                                              const float* __restrict__ u, const float* __restrict__ v,
                                              float* __restrict__ outB){
  __shared__ float Tt[64][65];
  const int t = threadIdx.x;
  const int j0t = blockIdx.y*64, d0 = blockIdx.x*128;
  const int jc = t & 63, ig = t >> 6;
  const int dg = t & 31, jg = t >> 5;
  float4 acc[8];
  #pragma unroll
  for (int m=0;m<8;m++) acc[m] = make_float4(0.f,0.f,0.f,0.f);
  for (int i0 = 0; i0 < NN; i0 += 64){
    __syncthreads();
    #pragma unroll
    for (int m=0;m<16;m++){
      int i = i0 + ig*16 + m;
      U32 kb = ((U32)Kp[(size_t)i*NN + j0t + jc]) << 16;
      Tt[jc][ig*16+m] = __uint_as_float(kb) * u[i];
    }
    __syncthreads();
    #pragma unroll 4
    for (int ii = 0; ii < 64; ++ii){
      float4 b4 = *(const float4*)(B + (size_t)(i0+ii)*DD + d0 + dg*4);
      #pragma unroll
      for (int m=0;m<8;m++){
        float tv = Tt[jg*8+m][ii];
        acc[m].x = fmaf(tv, b4.x, acc[m].x);
        acc[m].y = fmaf(tv, b4.y, acc[m].y);
        acc[m].z = fmaf(tv, b4.z, acc[m].z);
        acc[m].w = fmaf(tv, b4.w, acc[m].w);
      }
    }
  }
  #pragma unroll
  for (int m=0;m<8;m++){
    int j = j0t + jg*8 + m;
    float vj = v[j];
    acc[m].x *= vj; acc[m].y *= vj; acc[m].z *= vj; acc[m].w *= vj;
    *(float4*)(outB + (size_t)j*DD + d0 + dg*4) = acc[m];
  }
}

extern "C" void kernel_launch(void* const* d_in, const int* in_sizes, int n_in,
                              void* d_out, int out_size, void* d_ws, size_t ws_size,
                              hipStream_t stream) {
  const float* A = (const float*)d_in[0];
  const float* B = (const float*)d_in[1];
  float* out = (float*)d_out;
  char* ws = (char*)d_ws;
  // ws layout (~136.5 MB), K buffer reused in place u16 q -> bf16 K':
  U16*  q     = (U16*) (ws);                          // 8192*8192*2 = 134217728
  float* part = (float*)(ws + 134217728);             // 64*8192*4   = 2097152
  float* u    = (float*)(ws + 136314880);             // 32768
  float* v    = (float*)(ws + 136347648);             // 32768
  float* sqA  = (float*)(ws + 136380416);             // 32768
  float* sqB  = (float*)(ws + 136413184);             // 32768
  U32*  slots = (U32*) (ws + 136445952);              // scalars

  k_init<<<32, 256, 0, stream>>>(u, slots);
  k_sqsum<<<4096, 256, 0, stream>>>(A, B, sqA, sqB, slots);
  k_dist<<<dim3(64,64), 256, 0, stream>>>(A, B, q, sqA, sqB, slots);
  k_buildK<<<32768, 256, 0, stream>>>((U32*)q, slots);
  for (int it = 0; it < 200; ++it){
    k_col<<<dim3(8,64), 256, 0, stream>>>((const U32*)q, u, part);
    k_vfin<<<64, 128, 0, stream>>>(part, v);
    k_row<<<1024, 512, 0, stream>>>((const U32*)q, v, u);
  }
  k_outA<<<dim3(6,128), 256, 0, stream>>>(q, A, u, v, out);
  k_outB<<<dim3(6,128), 256, 0, stream>>>(q, B, u, v, out + (size_t)NN*DD);
}